// Round 2
// baseline (740.117 us; speedup 1.0000x reference)
//
#include <hip/hip_runtime.h>

// ---------------- common helpers ----------------

typedef __attribute__((ext_vector_type(8))) short s16x8;   // 8 x bf16 (4 VGPRs)
typedef __attribute__((ext_vector_type(4))) float f32x4;   // MFMA accumulator

__device__ __forceinline__ unsigned short f2bf(float f) {
  union { float f; unsigned u; } v; v.f = f;
  unsigned r = v.u + 0x7fffu + ((v.u >> 16) & 1u);   // round-to-nearest-even
  return (unsigned short)(r >> 16);
}
__device__ __forceinline__ float bf2f(unsigned short h) {
  union { unsigned u; float f; } v; v.u = ((unsigned)h) << 16; return v.f;
}
__device__ __forceinline__ void gload_lds16(const void* g, void* l) {
  __builtin_amdgcn_global_load_lds(
      (const __attribute__((address_space(1))) void*)g,
      (__attribute__((address_space(3))) void*)l, 16, 0, 0);
}

// ---------------- fp32 -> bf16 convert (weights) ----------------

__global__ void conv_bf16(const float4* __restrict__ src, ushort4* __restrict__ dst, int n4) {
  int i = blockIdx.x * blockDim.x + threadIdx.x;
  if (i >= n4) return;
  float4 v = src[i];
  ushort4 o;
  o.x = f2bf(v.x); o.y = f2bf(v.y); o.z = f2bf(v.z); o.w = f2bf(v.w);
  dst[i] = o;
}

// ---------------- time-shift mix -> one x (bf16) ----------------

__global__ void prep_mix(const float4* __restrict__ hidden,
                         const float4* __restrict__ tm,
                         ushort4* __restrict__ x,
                         int S, int H4, long long total4) {
  long long i = (long long)blockIdx.x * blockDim.x + threadIdx.x;
  if (i >= total4) return;
  int h4 = (int)(i % H4);
  long long sb = i / H4;          // b*S + s
  int s = (int)(sb % S);
  float4 cur = hidden[i];
  float4 prev = make_float4(0.f, 0.f, 0.f, 0.f);
  if (s > 0) prev = hidden[i - H4];
  float4 m = tm[h4];
  ushort4 o;
  o.x = f2bf(cur.x * m.x + prev.x * (1.f - m.x));
  o.y = f2bf(cur.y * m.y + prev.y * (1.f - m.y));
  o.z = f2bf(cur.z * m.z + prev.z * (1.f - m.z));
  o.w = f2bf(cur.w * m.w + prev.w * (1.f - m.w));
  x[i] = o;
}

// ---------------- bf16 NT GEMM: C[M,N] = A[M,K] * B[N,K]^T ----------------
// m97-style: 128x128 tile, BK=32, global_load_lds width-16 staging,
// 16x16x32 bf16 MFMA, 4 waves each computing a 64x64 sub-tile (4x4 frags).
// EPI: 0 = fp32 -> Cf; 1 = sigmoid -> bf16 Cb; 2 = plain bf16 -> Cb.

#define TM 128
#define TN 128
#define TK 32

template <int EPI>
__global__ __launch_bounds__(256) void gemm_bt(
    const unsigned short* __restrict__ A, const unsigned short* __restrict__ B,
    float* __restrict__ Cf, unsigned short* __restrict__ Cb,
    int M, int N, int K) {
  __shared__ unsigned short lA[TM * TK];  // 8 KiB, row-major 128x32
  __shared__ unsigned short lB[TN * TK];  // 8 KiB

  const int tid = threadIdx.x;
  const int wave = tid >> 6;
  const int lane = tid & 63;
  const int bm = blockIdx.x * TM;
  const int bn = blockIdx.y * TN;
  const int wm = (wave >> 1) * 64;     // wave's 64x64 sub-tile
  const int wn = (wave & 1) * 64;
  const int lrow = lane & 15;          // row within a 16-frag
  const int lk = (lane >> 4) * 8;      // k-offset within frag

  f32x4 acc[4][4] = {};

  for (int k0 = 0; k0 < K; k0 += TK) {
    // stage A-tile and B-tile: chunk c = seg*64 + lane; LDS elem = c*8 = seg*512 + lane*8
#pragma unroll
    for (int i = 0; i < 2; ++i) {
      int seg = wave + i * 4;
      int c = seg * 64 + lane;
      int row = c >> 2, col8 = c & 3;
      gload_lds16(A + (long long)(bm + row) * K + k0 + col8 * 8, &lA[seg * 512]);
      gload_lds16(B + (long long)(bn + row) * K + k0 + col8 * 8, &lB[seg * 512]);
    }
    __syncthreads();  // drains vmcnt -> staging visible

    s16x8 af[4], bfr[4];
#pragma unroll
    for (int t = 0; t < 4; ++t) {
      af[t]  = *(const s16x8*)&lA[(wm + t * 16 + lrow) * TK + lk];
      bfr[t] = *(const s16x8*)&lB[(wn + t * 16 + lrow) * TK + lk];
    }
#pragma unroll
    for (int mt = 0; mt < 4; ++mt)
#pragma unroll
      for (int nt = 0; nt < 4; ++nt)
        acc[mt][nt] = __builtin_amdgcn_mfma_f32_16x16x32_bf16(af[mt], bfr[nt], acc[mt][nt], 0, 0, 0);
    __syncthreads();  // before next-tile overwrite
  }

  // epilogue: C/D layout col=lane&15, row=(lane>>4)*4+reg
#pragma unroll
  for (int mt = 0; mt < 4; ++mt)
#pragma unroll
    for (int nt = 0; nt < 4; ++nt)
#pragma unroll
      for (int r = 0; r < 4; ++r) {
        int row = bm + wm + mt * 16 + ((lane >> 4) * 4 + r);
        int col = bn + wn + nt * 16 + (lane & 15);
        float v = acc[mt][nt][r];
        long long idx = (long long)row * N + col;
        if (EPI == 0) {
          Cf[idx] = v;
        } else if (EPI == 1) {
          float s = 1.f / (1.f + __expf(-v));
          Cb[idx] = f2bf(s);
        } else {
          Cb[idx] = f2bf(v);
        }
      }
}

// ---------------- chunked WKV scan ----------------
// C chunks of L tokens. Phase1: per-chunk local (num,den,m) from empty state.
// Phase2: sequential combine across chunks -> incoming state per chunk.
// Phase3: re-scan chunk with incoming state, emit r*out (bf16).
// k is fp32 (in d_out scratch), v is bf16.

#define NEG_INF_F (-1e38f)

__global__ void scan_phase1(const float* __restrict__ kf,
                            const unsigned short* __restrict__ vb,
                            const float* __restrict__ td,
                            float* __restrict__ locN, float* __restrict__ locD,
                            float* __restrict__ locM,
                            int S, int D, int C, int L) {
  int t = blockIdx.x * blockDim.x + threadIdx.x;  // over B*C*D
  int d = t % D;
  int c = (t / D) % C;
  int b = t / (D * C);
  float w = -__expf(td[d]);
  float num = 0.f, den = 0.f, m = NEG_INF_F;
  long long base = ((long long)(b * S + c * L)) * D + d;
  for (int i = 0; i < L; ++i) {
    float kk = kf[base];
    float vv = bf2f(vb[base]);
    base += D;
    float mn = fmaxf(m + w, kk);
    float e1 = __expf(m + w - mn);
    float e2 = __expf(kk - mn);
    num = e1 * num + e2 * vv;
    den = e1 * den + e2;
    m = mn;
  }
  int o = (b * C + c) * D + d;
  locN[o] = num; locD[o] = den; locM[o] = m;
}

__global__ void scan_phase2(const float* __restrict__ td,
                            const float* __restrict__ locN, const float* __restrict__ locD,
                            const float* __restrict__ locM,
                            float* __restrict__ inN, float* __restrict__ inD,
                            float* __restrict__ inM,
                            int Bc, int D, int C, int L) {
  int t = blockIdx.x * blockDim.x + threadIdx.x;  // over B*D
  if (t >= Bc * D) return;
  int d = t % D, b = t / D;
  float w = -__expf(td[d]);
  float Lw = (float)L * w;
  float num = 0.f, den = 0.f, m = NEG_INF_F;
  for (int c = 0; c < C; ++c) {
    int o = (b * C + c) * D + d;
    inN[o] = num; inD[o] = den; inM[o] = m;
    float sm = m + Lw;                 // decay incoming state over whole chunk
    float lm = locM[o];
    float m2 = fmaxf(sm, lm);
    float e1 = __expf(sm - m2);
    float e2 = __expf(lm - m2);
    num = e1 * num + e2 * locN[o];
    den = e1 * den + e2 * locD[o];
    m = m2;
  }
}

__global__ void scan_phase3(const float* __restrict__ kf,
                            const unsigned short* __restrict__ vb,
                            const unsigned short* __restrict__ rb,
                            const float* __restrict__ td, const float* __restrict__ tfirst,
                            const float* __restrict__ inN, const float* __restrict__ inD,
                            const float* __restrict__ inM,
                            unsigned short* __restrict__ rr,
                            int S, int D, int C, int L) {
  int t = blockIdx.x * blockDim.x + threadIdx.x;  // over B*C*D
  int d = t % D;
  int c = (t / D) % C;
  int b = t / (D * C);
  float w = -__expf(td[d]);
  float tfd = tfirst[d];
  int o = (b * C + c) * D + d;
  float num = inN[o], den = inD[o], m = inM[o];
  long long base = ((long long)(b * S + c * L)) * D + d;
  for (int i = 0; i < L; ++i) {
    float kk = kf[base];
    float vv = bf2f(vb[base]);
    float rv = bf2f(rb[base]);
    float ktf = kk + tfd;
    float mo = fmaxf(m, ktf);
    float e1 = __expf(m - mo);
    float e2 = __expf(ktf - mo);
    float out = (e1 * num + e2 * vv) / (e1 * den + e2);
    rr[base] = f2bf(out * rv);
    float mn = fmaxf(m + w, kk);
    e1 = __expf(m + w - mn);
    e2 = __expf(kk - mn);
    num = e1 * num + e2 * vv;
    den = e1 * den + e2;
    m = mn;
    base += D;
  }
}

// ---------------- launch ----------------

extern "C" void kernel_launch(void* const* d_in, const int* in_sizes, int n_in,
                              void* d_out, int out_size, void* d_ws, size_t ws_size,
                              hipStream_t stream) {
  const float* hidden = (const float*)d_in[0];
  const float* td  = (const float*)d_in[1];
  const float* tfi = (const float*)d_in[2];
  const float* tmk = (const float*)d_in[3];
  const float* tmv = (const float*)d_in[4];
  const float* tmr = (const float*)d_in[5];
  const float* Wk  = (const float*)d_in[6];
  const float* Wv  = (const float*)d_in[7];
  const float* Wr  = (const float*)d_in[8];
  const float* Wo  = (const float*)d_in[9];
  float* out = (float*)d_out;

  const int H = in_sizes[1];                 // 2048
  const int D = H;
  const long long BS = (long long)in_sizes[0] / H;  // 8192 = B*S
  const int S = 2048;
  const int B = (int)(BS / S);               // 4
  const int C = 32, L = S / C;               // 32 chunks of 64

  // workspace layout (110 MiB total):
  //   W_b  [0,   8) MiB  — one bf16 weight slot, reused per GEMM
  //   X    [8,  40) MiB  — xk -> xv -> xr -> rr (bf16, B*S*H)
  //   vb   [40, 72) MiB  — v bf16
  //   rb   [72, 104) MiB — sigmoid(r) bf16
  //   states [104,110) MiB — 6 x 1 MiB scan state
  // k (fp32, 64 MiB) lives in d_out; dead before final GEMM overwrites it.
  char* ws = (char*)d_ws;
  const size_t MB = 1u << 20;
  unsigned short* W_b = (unsigned short*)(ws + 0 * MB);
  unsigned short* X   = (unsigned short*)(ws + 8 * MB);
  unsigned short* vb  = (unsigned short*)(ws + 40 * MB);
  unsigned short* rb  = (unsigned short*)(ws + 72 * MB);
  float* locN         = (float*)(ws + 104 * MB);
  float* locD         = (float*)(ws + 105 * MB);
  float* locM         = (float*)(ws + 106 * MB);
  float* inN          = (float*)(ws + 107 * MB);
  float* inD          = (float*)(ws + 108 * MB);
  float* inM          = (float*)(ws + 109 * MB);
  float* kf           = out;   // fp32 k scratch in d_out
  unsigned short* rr  = X;     // r*rwkv result reuses X slot

  int n4w = H * H / 4;
  int cbk = (n4w + 255) / 256;
  long long total4 = BS * H / 4;
  int pbk = (int)((total4 + 255) / 256);
  dim3 g((unsigned)(BS / TM), (unsigned)(D / TN));

  // k = xk @ Wk^T  (fp32 -> d_out scratch)
  prep_mix<<<pbk, 256, 0, stream>>>((const float4*)hidden, (const float4*)tmk,
                                    (ushort4*)X, S, H / 4, total4);
  conv_bf16<<<cbk, 256, 0, stream>>>((const float4*)Wk, (ushort4*)W_b, n4w);
  gemm_bt<0><<<g, 256, 0, stream>>>(X, W_b, kf, nullptr, (int)BS, D, H);

  // v = xv @ Wv^T  (bf16)
  prep_mix<<<pbk, 256, 0, stream>>>((const float4*)hidden, (const float4*)tmv,
                                    (ushort4*)X, S, H / 4, total4);
  conv_bf16<<<cbk, 256, 0, stream>>>((const float4*)Wv, (ushort4*)W_b, n4w);
  gemm_bt<2><<<g, 256, 0, stream>>>(X, W_b, nullptr, vb, (int)BS, D, H);

  // r = sigmoid(xr @ Wr^T)  (bf16)
  prep_mix<<<pbk, 256, 0, stream>>>((const float4*)hidden, (const float4*)tmr,
                                    (ushort4*)X, S, H / 4, total4);
  conv_bf16<<<cbk, 256, 0, stream>>>((const float4*)Wr, (ushort4*)W_b, n4w);
  gemm_bt<1><<<g, 256, 0, stream>>>(X, W_b, nullptr, rb, (int)BS, D, H);

  // chunked WKV scan, fused r * rwkv -> rr (bf16, reuses X)
  int nscan = B * C * D;
  scan_phase1<<<nscan / 256, 256, 0, stream>>>(kf, vb, td, locN, locD, locM, S, D, C, L);
  scan_phase2<<<(B * D + 255) / 256, 256, 0, stream>>>(td, locN, locD, locM, inN, inD, inM, B, D, C, L);
  scan_phase3<<<nscan / 256, 256, 0, stream>>>(kf, vb, rb, td, tfi, inN, inD, inM, rr, S, D, C, L);

  // out = (r * rwkv) @ Wo^T  (fp32 -> d_out; kf dead now)
  conv_bf16<<<cbk, 256, 0, stream>>>((const float4*)Wo, (ushort4*)W_b, n4w);
  gemm_bt<0><<<g, 256, 0, stream>>>(rr, W_b, out, nullptr, (int)BS, H, D);
}

// Round 3
// 702.569 us; speedup vs baseline: 1.0534x; 1.0534x over previous
//
#include <hip/hip_runtime.h>

// ---------------- common helpers ----------------

typedef __attribute__((ext_vector_type(8))) short s16x8;   // 8 x bf16 (4 VGPRs)
typedef __attribute__((ext_vector_type(4))) float f32x4;   // MFMA accumulator

__device__ __forceinline__ unsigned short f2bf(float f) {
  union { float f; unsigned u; } v; v.f = f;
  unsigned r = v.u + 0x7fffu + ((v.u >> 16) & 1u);   // round-to-nearest-even
  return (unsigned short)(r >> 16);
}
__device__ __forceinline__ float bf2f(unsigned short h) {
  union { unsigned u; float f; } v; v.u = ((unsigned)h) << 16; return v.f;
}
__device__ __forceinline__ void gload_lds16(const void* g, void* l) {
  __builtin_amdgcn_global_load_lds(
      (const __attribute__((address_space(1))) void*)g,
      (__attribute__((address_space(3))) void*)l, 16, 0, 0);
}

// ---------------- fp32 -> bf16 convert (weights) ----------------

__global__ void conv_bf16(const float4* __restrict__ src, ushort4* __restrict__ dst, int n4) {
  int i = blockIdx.x * blockDim.x + threadIdx.x;
  if (i >= n4) return;
  float4 v = src[i];
  ushort4 o;
  o.x = f2bf(v.x); o.y = f2bf(v.y); o.z = f2bf(v.z); o.w = f2bf(v.w);
  dst[i] = o;
}

// ---------------- fused time-shift mix -> xk, xv, xr (bf16) ----------------

__global__ void prep_mix3(const float4* __restrict__ hidden,
                          const float4* __restrict__ tmk,
                          const float4* __restrict__ tmv,
                          const float4* __restrict__ tmr,
                          ushort4* __restrict__ xk, ushort4* __restrict__ xv,
                          ushort4* __restrict__ xr,
                          int S, int H4, long long total4) {
  long long i = (long long)blockIdx.x * blockDim.x + threadIdx.x;
  if (i >= total4) return;
  int h4 = (int)(i % H4);
  long long sb = i / H4;          // b*S + s
  int s = (int)(sb % S);
  float4 cur = hidden[i];
  float4 prev = make_float4(0.f, 0.f, 0.f, 0.f);
  if (s > 0) prev = hidden[i - H4];
  float4 mk = tmk[h4], mv = tmv[h4], mr = tmr[h4];
  ushort4 ok, ov, orr;
  ok.x = f2bf(cur.x * mk.x + prev.x * (1.f - mk.x));
  ok.y = f2bf(cur.y * mk.y + prev.y * (1.f - mk.y));
  ok.z = f2bf(cur.z * mk.z + prev.z * (1.f - mk.z));
  ok.w = f2bf(cur.w * mk.w + prev.w * (1.f - mk.w));
  ov.x = f2bf(cur.x * mv.x + prev.x * (1.f - mv.x));
  ov.y = f2bf(cur.y * mv.y + prev.y * (1.f - mv.y));
  ov.z = f2bf(cur.z * mv.z + prev.z * (1.f - mv.z));
  ov.w = f2bf(cur.w * mv.w + prev.w * (1.f - mv.w));
  orr.x = f2bf(cur.x * mr.x + prev.x * (1.f - mr.x));
  orr.y = f2bf(cur.y * mr.y + prev.y * (1.f - mr.y));
  orr.z = f2bf(cur.z * mr.z + prev.z * (1.f - mr.z));
  orr.w = f2bf(cur.w * mr.w + prev.w * (1.f - mr.w));
  xk[i] = ok; xv[i] = ov; xr[i] = orr;
}

// ---------------- bf16 NT GEMM: C[M,N] = A[M,K] * B[N,K]^T ----------------
// 128x128 tile, BK=32, global_load_lds width-16 staging, 16x16x32 bf16 MFMA.
// LDS layout XOR-swizzled: chunk for (row, col8) lives at slot col8^((row>>1)&3).
// Staging gathers the swizzled global chunk (lane->LDS mapping fixed by HW);
// readers apply the same swizzle -> 2-way bank aliasing only (free).
// EPI: 0 = fp32 -> Cf; 1 = sigmoid -> bf16 Cb; 2 = plain bf16 -> Cb.

#define TM 128
#define TN 128
#define TK 32

template <int EPI>
__global__ __launch_bounds__(256) void gemm_bt(
    const unsigned short* __restrict__ A, const unsigned short* __restrict__ B,
    float* __restrict__ Cf, unsigned short* __restrict__ Cb,
    int M, int N, int K) {
  __shared__ unsigned short lA[TM * TK];  // 8 KiB
  __shared__ unsigned short lB[TN * TK];  // 8 KiB

  const int tid = threadIdx.x;
  const int wave = tid >> 6;
  const int lane = tid & 63;
  const int bm = blockIdx.x * TM;
  const int bn = blockIdx.y * TN;
  const int wm = (wave >> 1) * 64;     // wave's 64x64 sub-tile
  const int wn = (wave & 1) * 64;
  const int lrow = lane & 15;          // row within a 16-frag
  const int q = lane >> 4;             // which 8-elem k-chunk (0..3)

  f32x4 acc[4][4] = {};

  // staging constants: c = seg*64+lane; row = c>>2; slot = c&3
  const int st_row = lane >> 2;        // + seg*16
  const int st_slot = lane & 3;

  for (int k0 = 0; k0 < K; k0 += TK) {
#pragma unroll
    for (int i = 0; i < 2; ++i) {
      int seg = wave + i * 4;
      int row = seg * 16 + st_row;
      int col8 = st_slot ^ ((row >> 1) & 3);   // XOR swizzle
      gload_lds16(A + (long long)(bm + row) * K + k0 + col8 * 8, &lA[seg * 512]);
      gload_lds16(B + (long long)(bn + row) * K + k0 + col8 * 8, &lB[seg * 512]);
    }
    __syncthreads();  // drains vmcnt -> staging visible

    s16x8 af[4], bfr[4];
#pragma unroll
    for (int t = 0; t < 4; ++t) {
      int ar = wm + t * 16 + lrow;
      int br = wn + t * 16 + lrow;
      af[t]  = *(const s16x8*)&lA[ar * TK + (q ^ ((ar >> 1) & 3)) * 8];
      bfr[t] = *(const s16x8*)&lB[br * TK + (q ^ ((br >> 1) & 3)) * 8];
    }
#pragma unroll
    for (int mt = 0; mt < 4; ++mt)
#pragma unroll
      for (int nt = 0; nt < 4; ++nt)
        acc[mt][nt] = __builtin_amdgcn_mfma_f32_16x16x32_bf16(af[mt], bfr[nt], acc[mt][nt], 0, 0, 0);
    __syncthreads();  // before next-tile overwrite
  }

  // epilogue: C/D layout col=lane&15, row=(lane>>4)*4+reg
#pragma unroll
  for (int mt = 0; mt < 4; ++mt)
#pragma unroll
    for (int nt = 0; nt < 4; ++nt)
#pragma unroll
      for (int r = 0; r < 4; ++r) {
        int row = bm + wm + mt * 16 + ((lane >> 4) * 4 + r);
        int col = bn + wn + nt * 16 + (lane & 15);
        float v = acc[mt][nt][r];
        long long idx = (long long)row * N + col;
        if (EPI == 0) {
          Cf[idx] = v;
        } else if (EPI == 1) {
          float s = 1.f / (1.f + __expf(-v));
          Cb[idx] = f2bf(s);
        } else {
          Cb[idx] = f2bf(v);
        }
      }
}

// ---------------- chunked WKV scan ----------------
// C chunks of L tokens. Phase1: per-chunk local (num,den,m) from empty state.
// Phase2: sequential combine across chunks -> incoming state per chunk.
// Phase3: re-scan chunk with incoming state, emit r*out (bf16).
// k is fp32 (in d_out scratch), v is bf16.

#define NEG_INF_F (-1e38f)

__global__ void scan_phase1(const float* __restrict__ kf,
                            const unsigned short* __restrict__ vb,
                            const float* __restrict__ td,
                            float* __restrict__ locN, float* __restrict__ locD,
                            float* __restrict__ locM,
                            int S, int D, int C, int L) {
  int t = blockIdx.x * blockDim.x + threadIdx.x;  // over B*C*D
  int d = t % D;
  int c = (t / D) % C;
  int b = t / (D * C);
  float w = -__expf(td[d]);
  float num = 0.f, den = 0.f, m = NEG_INF_F;
  long long base = ((long long)(b * S + c * L)) * D + d;
  for (int i = 0; i < L; ++i) {
    float kk = kf[base];
    float vv = bf2f(vb[base]);
    base += D;
    float mn = fmaxf(m + w, kk);
    float e1 = __expf(m + w - mn);
    float e2 = __expf(kk - mn);
    num = e1 * num + e2 * vv;
    den = e1 * den + e2;
    m = mn;
  }
  int o = (b * C + c) * D + d;
  locN[o] = num; locD[o] = den; locM[o] = m;
}

__global__ void scan_phase2(const float* __restrict__ td,
                            const float* __restrict__ locN, const float* __restrict__ locD,
                            const float* __restrict__ locM,
                            float* __restrict__ inN, float* __restrict__ inD,
                            float* __restrict__ inM,
                            int Bc, int D, int C, int L) {
  int t = blockIdx.x * blockDim.x + threadIdx.x;  // over B*D
  if (t >= Bc * D) return;
  int d = t % D, b = t / D;
  float w = -__expf(td[d]);
  float Lw = (float)L * w;
  float num = 0.f, den = 0.f, m = NEG_INF_F;
  for (int c = 0; c < C; ++c) {
    int o = (b * C + c) * D + d;
    inN[o] = num; inD[o] = den; inM[o] = m;
    float sm = m + Lw;                 // decay incoming state over whole chunk
    float lm = locM[o];
    float m2 = fmaxf(sm, lm);
    float e1 = __expf(sm - m2);
    float e2 = __expf(lm - m2);
    num = e1 * num + e2 * locN[o];
    den = e1 * den + e2 * locD[o];
    m = m2;
  }
}

__global__ void scan_phase3(const float* __restrict__ kf,
                            const unsigned short* __restrict__ vb,
                            const unsigned short* __restrict__ rb,
                            const float* __restrict__ td, const float* __restrict__ tfirst,
                            const float* __restrict__ inN, const float* __restrict__ inD,
                            const float* __restrict__ inM,
                            unsigned short* __restrict__ rr,
                            int S, int D, int C, int L) {
  int t = blockIdx.x * blockDim.x + threadIdx.x;  // over B*C*D
  int d = t % D;
  int c = (t / D) % C;
  int b = t / (D * C);
  float w = -__expf(td[d]);
  float tfd = tfirst[d];
  int o = (b * C + c) * D + d;
  float num = inN[o], den = inD[o], m = inM[o];
  long long base = ((long long)(b * S + c * L)) * D + d;
  for (int i = 0; i < L; ++i) {
    float kk = kf[base];
    float vv = bf2f(vb[base]);
    float rv = bf2f(rb[base]);
    float ktf = kk + tfd;
    float mo = fmaxf(m, ktf);
    float e1 = __expf(m - mo);
    float e2 = __expf(ktf - mo);
    float out = (e1 * num + e2 * vv) / (e1 * den + e2);
    rr[base] = f2bf(out * rv);
    float mn = fmaxf(m + w, kk);
    e1 = __expf(m + w - mn);
    e2 = __expf(kk - mn);
    num = e1 * num + e2 * vv;
    den = e1 * den + e2;
    m = mn;
    base += D;
  }
}

// ---------------- launch ----------------

extern "C" void kernel_launch(void* const* d_in, const int* in_sizes, int n_in,
                              void* d_out, int out_size, void* d_ws, size_t ws_size,
                              hipStream_t stream) {
  const float* hidden = (const float*)d_in[0];
  const float* td  = (const float*)d_in[1];
  const float* tfi = (const float*)d_in[2];
  const float* tmk = (const float*)d_in[3];
  const float* tmv = (const float*)d_in[4];
  const float* tmr = (const float*)d_in[5];
  const float* Wk  = (const float*)d_in[6];
  const float* Wv  = (const float*)d_in[7];
  const float* Wr  = (const float*)d_in[8];
  const float* Wo  = (const float*)d_in[9];
  float* out = (float*)d_out;

  const int H = in_sizes[1];                 // 2048
  const int D = H;
  const long long BS = (long long)in_sizes[0] / H;  // 8192 = B*S
  const int S = 2048;
  const int B = (int)(BS / S);               // 4
  const int C = 32, L = S / C;               // 32 chunks of 64

  // workspace layout (110 MiB total, proven safe in R1):
  //   W_b [0,8) | X [8,40) | Y [40,72) | Z [72,104) | states [104,110)
  // rotation: prep3 -> X=xk, Y=xv, Z=xr
  //   gemm k: X -> kf (d_out fp32)
  //   gemm v: Y -> X (bf16)      [xk dead]
  //   gemm r: Z -> Y (bf16)      [xv dead]
  //   scan:  kf, X(v), Y(r) -> Z (rr bf16)   [xr dead]
  //   gemm o: Z -> d_out         [kf dead]
  char* ws = (char*)d_ws;
  const size_t MB = 1u << 20;
  unsigned short* W_b = (unsigned short*)(ws + 0 * MB);
  unsigned short* X   = (unsigned short*)(ws + 8 * MB);
  unsigned short* Y   = (unsigned short*)(ws + 40 * MB);
  unsigned short* Z   = (unsigned short*)(ws + 72 * MB);
  float* locN         = (float*)(ws + 104 * MB);
  float* locD         = (float*)(ws + 105 * MB);
  float* locM         = (float*)(ws + 106 * MB);
  float* inN          = (float*)(ws + 107 * MB);
  float* inD          = (float*)(ws + 108 * MB);
  float* inM          = (float*)(ws + 109 * MB);
  float* kf           = out;   // fp32 k scratch in d_out

  int n4w = H * H / 4;
  int cbk = (n4w + 255) / 256;
  long long total4 = BS * H / 4;
  int pbk = (int)((total4 + 255) / 256);
  dim3 g((unsigned)(BS / TM), (unsigned)(D / TN));

  // fused time-shift mix (one pass over hidden)
  prep_mix3<<<pbk, 256, 0, stream>>>((const float4*)hidden,
                                     (const float4*)tmk, (const float4*)tmv, (const float4*)tmr,
                                     (ushort4*)X, (ushort4*)Y, (ushort4*)Z, S, H / 4, total4);

  // k = xk @ Wk^T  (fp32 -> d_out scratch)
  conv_bf16<<<cbk, 256, 0, stream>>>((const float4*)Wk, (ushort4*)W_b, n4w);
  gemm_bt<0><<<g, 256, 0, stream>>>(X, W_b, kf, nullptr, (int)BS, D, H);

  // v = xv @ Wv^T  (bf16 -> X)
  conv_bf16<<<cbk, 256, 0, stream>>>((const float4*)Wv, (ushort4*)W_b, n4w);
  gemm_bt<2><<<g, 256, 0, stream>>>(Y, W_b, nullptr, X, (int)BS, D, H);

  // r = sigmoid(xr @ Wr^T)  (bf16 -> Y)
  conv_bf16<<<cbk, 256, 0, stream>>>((const float4*)Wr, (ushort4*)W_b, n4w);
  gemm_bt<1><<<g, 256, 0, stream>>>(Z, W_b, nullptr, Y, (int)BS, D, H);

  // chunked WKV scan, fused r * rwkv -> Z (bf16)
  int nscan = B * C * D;
  scan_phase1<<<nscan / 256, 256, 0, stream>>>(kf, X, td, locN, locD, locM, S, D, C, L);
  scan_phase2<<<(B * D + 255) / 256, 256, 0, stream>>>(td, locN, locD, locM, inN, inD, inM, B, D, C, L);
  scan_phase3<<<nscan / 256, 256, 0, stream>>>(kf, X, Y, td, tfi, inN, inD, inM, Z, S, D, C, L);

  // out = (r * rwkv) @ Wo^T  (fp32 -> d_out; kf dead now)
  conv_bf16<<<cbk, 256, 0, stream>>>((const float4*)Wo, (ushort4*)W_b, n4w);
  gemm_bt<0><<<g, 256, 0, stream>>>(Z, W_b, out, nullptr, (int)BS, H, D);
}

// Round 4
// 648.249 us; speedup vs baseline: 1.1417x; 1.0838x over previous
//
#include <hip/hip_runtime.h>

// ---------------- common helpers ----------------

typedef __attribute__((ext_vector_type(8))) short s16x8;    // 8 x bf16 (4 VGPRs)
typedef __attribute__((ext_vector_type(16))) float f32x16;  // 32x32 MFMA accumulator

__device__ __forceinline__ unsigned short f2bf(float f) {
  union { float f; unsigned u; } v; v.f = f;
  unsigned r = v.u + 0x7fffu + ((v.u >> 16) & 1u);   // round-to-nearest-even
  return (unsigned short)(r >> 16);
}
__device__ __forceinline__ float bf2f(unsigned short h) {
  union { unsigned u; float f; } v; v.u = ((unsigned)h) << 16; return v.f;
}
__device__ __forceinline__ void gload_lds16(const void* g, void* l) {
  __builtin_amdgcn_global_load_lds(
      (const __attribute__((address_space(1))) void*)g,
      (__attribute__((address_space(3))) void*)l, 16, 0, 0);
}

// ---------------- fp32 -> bf16 convert (weights) ----------------

__global__ void conv_bf16(const float4* __restrict__ src, ushort4* __restrict__ dst, int n4) {
  int i = blockIdx.x * blockDim.x + threadIdx.x;
  if (i >= n4) return;
  float4 v = src[i];
  ushort4 o;
  o.x = f2bf(v.x); o.y = f2bf(v.y); o.z = f2bf(v.z); o.w = f2bf(v.w);
  dst[i] = o;
}

// ---------------- fused time-shift mix -> xk, xv, xr (bf16) ----------------

__global__ void prep_mix3(const float4* __restrict__ hidden,
                          const float4* __restrict__ tmk,
                          const float4* __restrict__ tmv,
                          const float4* __restrict__ tmr,
                          ushort4* __restrict__ xk, ushort4* __restrict__ xv,
                          ushort4* __restrict__ xr,
                          int S, int H4, long long total4) {
  long long i = (long long)blockIdx.x * blockDim.x + threadIdx.x;
  if (i >= total4) return;
  int h4 = (int)(i % H4);
  long long sb = i / H4;          // b*S + s
  int s = (int)(sb % S);
  float4 cur = hidden[i];
  float4 prev = make_float4(0.f, 0.f, 0.f, 0.f);
  if (s > 0) prev = hidden[i - H4];
  float4 mk = tmk[h4], mv = tmv[h4], mr = tmr[h4];
  ushort4 ok, ov, orr;
  ok.x = f2bf(cur.x * mk.x + prev.x * (1.f - mk.x));
  ok.y = f2bf(cur.y * mk.y + prev.y * (1.f - mk.y));
  ok.z = f2bf(cur.z * mk.z + prev.z * (1.f - mk.z));
  ok.w = f2bf(cur.w * mk.w + prev.w * (1.f - mk.w));
  ov.x = f2bf(cur.x * mv.x + prev.x * (1.f - mv.x));
  ov.y = f2bf(cur.y * mv.y + prev.y * (1.f - mv.y));
  ov.z = f2bf(cur.z * mv.z + prev.z * (1.f - mv.z));
  ov.w = f2bf(cur.w * mv.w + prev.w * (1.f - mv.w));
  orr.x = f2bf(cur.x * mr.x + prev.x * (1.f - mr.x));
  orr.y = f2bf(cur.y * mr.y + prev.y * (1.f - mr.y));
  orr.z = f2bf(cur.z * mr.z + prev.z * (1.f - mr.z));
  orr.w = f2bf(cur.w * mr.w + prev.w * (1.f - mr.w));
  xk[i] = ok; xv[i] = ov; xr[i] = orr;
}

// ---------------- bf16 NT GEMM: C[M,N] = A[M,K] * B[N,K]^T ----------------
// 128x128 tile, BK=32, global_load_lds width-16 staging, 32x32x16 bf16 MFMA.
// Each of 4 waves computes a 64x64 sub-tile as 2x2 tiles of 32x32.
// LDS XOR-swizzled (R2: verified 0 bank conflicts): chunk (row, c) at slot
// c ^ ((row>>1)&3). Staging fetches the swizzled global chunk (HW lane->LDS
// mapping is fixed); readers apply the same swizzle.
// EPI: 0 = fp32 -> Cf; 1 = sigmoid -> bf16 Cb; 2 = plain bf16 -> Cb.

#define TM 128
#define TN 128
#define TK 32

template <int EPI>
__global__ __launch_bounds__(256) void gemm_bt(
    const unsigned short* __restrict__ A, const unsigned short* __restrict__ B,
    float* __restrict__ Cf, unsigned short* __restrict__ Cb,
    int M, int N, int K) {
  __shared__ unsigned short lA[TM * TK];  // 8 KiB
  __shared__ unsigned short lB[TN * TK];  // 8 KiB

  const int tid = threadIdx.x;
  const int wave = tid >> 6;
  const int lane = tid & 63;
  const int bm = blockIdx.x * TM;
  const int bn = blockIdx.y * TN;
  const int wm = (wave >> 1) * 64;     // wave's 64x64 sub-tile
  const int wn = (wave & 1) * 64;
  const int lrow = lane & 31;          // m/n within a 32-tile
  const int lq = lane >> 5;            // k-chunk half selector (0/1)

  f32x16 acc[2][2] = {};

  // staging: seg in {wave, wave+4}; row = seg*16 + (lane>>2); slot = lane&3
  const int st_row0 = wave * 16 + (lane >> 2);
  const int st_row1 = (wave + 4) * 16 + (lane >> 2);
  const int st_c0 = (lane & 3) ^ ((st_row0 >> 1) & 3);
  const int st_c1 = (lane & 3) ^ ((st_row1 >> 1) & 3);
  const unsigned short* pA0 = A + (long long)(bm + st_row0) * K + st_c0 * 8;
  const unsigned short* pA1 = A + (long long)(bm + st_row1) * K + st_c1 * 8;
  const unsigned short* pB0 = B + (long long)(bn + st_row0) * K + st_c0 * 8;
  const unsigned short* pB1 = B + (long long)(bn + st_row1) * K + st_c1 * 8;

  // fragment LDS offsets (loop-invariant): row r, chunk c -> r*TK + (c^((r>>1)&3))*8
  int offA[2][2], offB[2][2];
#pragma unroll
  for (int t = 0; t < 2; ++t)
#pragma unroll
    for (int h = 0; h < 2; ++h) {
      int ar = wm + t * 32 + lrow;
      int br = wn + t * 32 + lrow;
      int c = h * 2 + lq;
      offA[t][h] = ar * TK + ((c ^ ((ar >> 1) & 3)) * 8);
      offB[t][h] = br * TK + ((c ^ ((br >> 1) & 3)) * 8);
    }

  for (int k0 = 0; k0 < K; k0 += TK) {
    gload_lds16(pA0, &lA[wave * 512]);
    gload_lds16(pA1, &lA[(wave + 4) * 512]);
    gload_lds16(pB0, &lB[wave * 512]);
    gload_lds16(pB1, &lB[(wave + 4) * 512]);
    pA0 += TK; pA1 += TK; pB0 += TK; pB1 += TK;
    __syncthreads();  // drains vmcnt -> staging visible

    s16x8 af[2][2], bfr[2][2];
#pragma unroll
    for (int t = 0; t < 2; ++t)
#pragma unroll
      for (int h = 0; h < 2; ++h) {
        af[t][h]  = *(const s16x8*)&lA[offA[t][h]];
        bfr[t][h] = *(const s16x8*)&lB[offB[t][h]];
      }
#pragma unroll
    for (int h = 0; h < 2; ++h)
#pragma unroll
      for (int mt = 0; mt < 2; ++mt)
#pragma unroll
        for (int nt = 0; nt < 2; ++nt)
          acc[mt][nt] = __builtin_amdgcn_mfma_f32_32x32x16_bf16(
              af[mt][h], bfr[nt][h], acc[mt][nt], 0, 0, 0);
    __syncthreads();  // before next-tile overwrite
  }

  // epilogue: 32x32 C/D layout col=lane&31, row=(reg&3)+8*(reg>>2)+4*(lane>>5)
#pragma unroll
  for (int mt = 0; mt < 2; ++mt)
#pragma unroll
    for (int nt = 0; nt < 2; ++nt)
#pragma unroll
      for (int r = 0; r < 16; ++r) {
        int row = bm + wm + mt * 32 + (r & 3) + 8 * (r >> 2) + 4 * lq;
        int col = bn + wn + nt * 32 + lrow;
        float v = acc[mt][nt][r];
        long long idx = (long long)row * N + col;
        if (EPI == 0) {
          Cf[idx] = v;
        } else if (EPI == 1) {
          float s = 1.f / (1.f + __expf(-v));
          Cb[idx] = f2bf(s);
        } else {
          Cb[idx] = f2bf(v);
        }
      }
}

// ---------------- chunked WKV scan ----------------

#define NEG_INF_F (-1e38f)

__global__ void scan_phase1(const float* __restrict__ kf,
                            const unsigned short* __restrict__ vb,
                            const float* __restrict__ td,
                            float* __restrict__ locN, float* __restrict__ locD,
                            float* __restrict__ locM,
                            int S, int D, int C, int L) {
  int t = blockIdx.x * blockDim.x + threadIdx.x;  // over B*C*D
  int d = t % D;
  int c = (t / D) % C;
  int b = t / (D * C);
  float w = -__expf(td[d]);
  float num = 0.f, den = 0.f, m = NEG_INF_F;
  long long base = ((long long)(b * S + c * L)) * D + d;
  for (int i = 0; i < L; ++i) {
    float kk = kf[base];
    float vv = bf2f(vb[base]);
    base += D;
    float mn = fmaxf(m + w, kk);
    float e1 = __expf(m + w - mn);
    float e2 = __expf(kk - mn);
    num = e1 * num + e2 * vv;
    den = e1 * den + e2;
    m = mn;
  }
  int o = (b * C + c) * D + d;
  locN[o] = num; locD[o] = den; locM[o] = m;
}

__global__ void scan_phase2(const float* __restrict__ td,
                            const float* __restrict__ locN, const float* __restrict__ locD,
                            const float* __restrict__ locM,
                            float* __restrict__ inN, float* __restrict__ inD,
                            float* __restrict__ inM,
                            int Bc, int D, int C, int L) {
  int t = blockIdx.x * blockDim.x + threadIdx.x;  // over B*D
  if (t >= Bc * D) return;
  int d = t % D, b = t / D;
  float w = -__expf(td[d]);
  float Lw = (float)L * w;
  float num = 0.f, den = 0.f, m = NEG_INF_F;
  for (int c = 0; c < C; ++c) {
    int o = (b * C + c) * D + d;
    inN[o] = num; inD[o] = den; inM[o] = m;
    float sm = m + Lw;                 // decay incoming state over whole chunk
    float lm = locM[o];
    float m2 = fmaxf(sm, lm);
    float e1 = __expf(sm - m2);
    float e2 = __expf(lm - m2);
    num = e1 * num + e2 * locN[o];
    den = e1 * den + e2 * locD[o];
    m = m2;
  }
}

__global__ void scan_phase3(const float* __restrict__ kf,
                            const unsigned short* __restrict__ vb,
                            const unsigned short* __restrict__ rb,
                            const float* __restrict__ td, const float* __restrict__ tfirst,
                            const float* __restrict__ inN, const float* __restrict__ inD,
                            const float* __restrict__ inM,
                            unsigned short* __restrict__ rr,
                            int S, int D, int C, int L) {
  int t = blockIdx.x * blockDim.x + threadIdx.x;  // over B*C*D
  int d = t % D;
  int c = (t / D) % C;
  int b = t / (D * C);
  float w = -__expf(td[d]);
  float tfd = tfirst[d];
  int o = (b * C + c) * D + d;
  float num = inN[o], den = inD[o], m = inM[o];
  long long base = ((long long)(b * S + c * L)) * D + d;
  for (int i = 0; i < L; ++i) {
    float kk = kf[base];
    float vv = bf2f(vb[base]);
    float rv = bf2f(rb[base]);
    float ktf = kk + tfd;
    float mo = fmaxf(m, ktf);
    float e1 = __expf(m - mo);
    float e2 = __expf(ktf - mo);
    float out = (e1 * num + e2 * vv) / (e1 * den + e2);
    rr[base] = f2bf(out * rv);
    float mn = fmaxf(m + w, kk);
    e1 = __expf(m + w - mn);
    e2 = __expf(kk - mn);
    num = e1 * num + e2 * vv;
    den = e1 * den + e2;
    m = mn;
    base += D;
  }
}

// ---------------- launch ----------------

extern "C" void kernel_launch(void* const* d_in, const int* in_sizes, int n_in,
                              void* d_out, int out_size, void* d_ws, size_t ws_size,
                              hipStream_t stream) {
  const float* hidden = (const float*)d_in[0];
  const float* td  = (const float*)d_in[1];
  const float* tfi = (const float*)d_in[2];
  const float* tmk = (const float*)d_in[3];
  const float* tmv = (const float*)d_in[4];
  const float* tmr = (const float*)d_in[5];
  const float* Wk  = (const float*)d_in[6];
  const float* Wv  = (const float*)d_in[7];
  const float* Wr  = (const float*)d_in[8];
  const float* Wo  = (const float*)d_in[9];
  float* out = (float*)d_out;

  const int H = in_sizes[1];                 // 2048
  const int D = H;
  const long long BS = (long long)in_sizes[0] / H;  // 8192 = B*S
  const int S = 2048;
  const int B = (int)(BS / S);               // 4
  const int C = 32, L = S / C;               // 32 chunks of 64

  // workspace layout (110 MiB, proven safe):
  //   W_b [0,8) | X [8,40) | Y [40,72) | Z [72,104) | states [104,110)
  // rotation: prep3 -> X=xk, Y=xv, Z=xr
  //   gemm k: X -> kf (d_out fp32); gemm v: Y -> X; gemm r: Z -> Y
  //   scan: kf, X(v), Y(r) -> Z (rr);  gemm o: Z -> d_out (kf dead)
  char* ws = (char*)d_ws;
  const size_t MB = 1u << 20;
  unsigned short* W_b = (unsigned short*)(ws + 0 * MB);
  unsigned short* X   = (unsigned short*)(ws + 8 * MB);
  unsigned short* Y   = (unsigned short*)(ws + 40 * MB);
  unsigned short* Z   = (unsigned short*)(ws + 72 * MB);
  float* locN         = (float*)(ws + 104 * MB);
  float* locD         = (float*)(ws + 105 * MB);
  float* locM         = (float*)(ws + 106 * MB);
  float* inN          = (float*)(ws + 107 * MB);
  float* inD          = (float*)(ws + 108 * MB);
  float* inM          = (float*)(ws + 109 * MB);
  float* kf           = out;   // fp32 k scratch in d_out

  int n4w = H * H / 4;
  int cbk = (n4w + 255) / 256;
  long long total4 = BS * H / 4;
  int pbk = (int)((total4 + 255) / 256);
  dim3 g((unsigned)(BS / TM), (unsigned)(D / TN));

  // fused time-shift mix (one pass over hidden)
  prep_mix3<<<pbk, 256, 0, stream>>>((const float4*)hidden,
                                     (const float4*)tmk, (const float4*)tmv, (const float4*)tmr,
                                     (ushort4*)X, (ushort4*)Y, (ushort4*)Z, S, H / 4, total4);

  // k = xk @ Wk^T  (fp32 -> d_out scratch)
  conv_bf16<<<cbk, 256, 0, stream>>>((const float4*)Wk, (ushort4*)W_b, n4w);
  gemm_bt<0><<<g, 256, 0, stream>>>(X, W_b, kf, nullptr, (int)BS, D, H);

  // v = xv @ Wv^T  (bf16 -> X)
  conv_bf16<<<cbk, 256, 0, stream>>>((const float4*)Wv, (ushort4*)W_b, n4w);
  gemm_bt<2><<<g, 256, 0, stream>>>(Y, W_b, nullptr, X, (int)BS, D, H);

  // r = sigmoid(xr @ Wr^T)  (bf16 -> Y)
  conv_bf16<<<cbk, 256, 0, stream>>>((const float4*)Wr, (ushort4*)W_b, n4w);
  gemm_bt<1><<<g, 256, 0, stream>>>(Z, W_b, nullptr, Y, (int)BS, D, H);

  // chunked WKV scan, fused r * rwkv -> Z (bf16)
  int nscan = B * C * D;
  scan_phase1<<<nscan / 256, 256, 0, stream>>>(kf, X, td, locN, locD, locM, S, D, C, L);
  scan_phase2<<<(B * D + 255) / 256, 256, 0, stream>>>(td, locN, locD, locM, inN, inD, inM, B, D, C, L);
  scan_phase3<<<nscan / 256, 256, 0, stream>>>(kf, X, Y, td, tfi, inN, inD, inM, Z, S, D, C, L);

  // out = (r * rwkv) @ Wo^T  (fp32 -> d_out; kf dead now)
  conv_bf16<<<cbk, 256, 0, stream>>>((const float4*)Wo, (ushort4*)W_b, n4w);
  gemm_bt<0><<<g, 256, 0, stream>>>(Z, W_b, out, nullptr, (int)BS, H, D);
}

// Round 5
// 645.820 us; speedup vs baseline: 1.1460x; 1.0038x over previous
//
#include <hip/hip_runtime.h>

// ---------------- common helpers ----------------

typedef __attribute__((ext_vector_type(8))) short s16x8;    // 8 x bf16 (4 VGPRs)
typedef __attribute__((ext_vector_type(16))) float f32x16;  // 32x32 MFMA accumulator

__device__ __forceinline__ unsigned short f2bf(float f) {
  union { float f; unsigned u; } v; v.f = f;
  unsigned r = v.u + 0x7fffu + ((v.u >> 16) & 1u);   // round-to-nearest-even
  return (unsigned short)(r >> 16);
}
__device__ __forceinline__ float bf2f(unsigned short h) {
  union { unsigned u; float f; } v; v.u = ((unsigned)h) << 16; return v.f;
}
__device__ __forceinline__ void gload_lds16(const void* g, void* l) {
  __builtin_amdgcn_global_load_lds(
      (const __attribute__((address_space(1))) void*)g,
      (__attribute__((address_space(3))) void*)l, 16, 0, 0);
}

// ---------------- fp32 -> bf16 convert (weights) ----------------

__global__ void conv_bf16(const float4* __restrict__ src, ushort4* __restrict__ dst, int n4) {
  int i = blockIdx.x * blockDim.x + threadIdx.x;
  if (i >= n4) return;
  float4 v = src[i];
  ushort4 o;
  o.x = f2bf(v.x); o.y = f2bf(v.y); o.z = f2bf(v.z); o.w = f2bf(v.w);
  dst[i] = o;
}

// ---------------- fused time-shift mix -> xk, xv, xr (bf16) ----------------

__global__ void prep_mix3(const float4* __restrict__ hidden,
                          const float4* __restrict__ tmk,
                          const float4* __restrict__ tmv,
                          const float4* __restrict__ tmr,
                          ushort4* __restrict__ xk, ushort4* __restrict__ xv,
                          ushort4* __restrict__ xr,
                          int S, int H4, long long total4) {
  long long i = (long long)blockIdx.x * blockDim.x + threadIdx.x;
  if (i >= total4) return;
  int h4 = (int)(i % H4);
  long long sb = i / H4;          // b*S + s
  int s = (int)(sb % S);
  float4 cur = hidden[i];
  float4 prev = make_float4(0.f, 0.f, 0.f, 0.f);
  if (s > 0) prev = hidden[i - H4];
  float4 mk = tmk[h4], mv = tmv[h4], mr = tmr[h4];
  ushort4 ok, ov, orr;
  ok.x = f2bf(cur.x * mk.x + prev.x * (1.f - mk.x));
  ok.y = f2bf(cur.y * mk.y + prev.y * (1.f - mk.y));
  ok.z = f2bf(cur.z * mk.z + prev.z * (1.f - mk.z));
  ok.w = f2bf(cur.w * mk.w + prev.w * (1.f - mk.w));
  ov.x = f2bf(cur.x * mv.x + prev.x * (1.f - mv.x));
  ov.y = f2bf(cur.y * mv.y + prev.y * (1.f - mv.y));
  ov.z = f2bf(cur.z * mv.z + prev.z * (1.f - mv.z));
  ov.w = f2bf(cur.w * mv.w + prev.w * (1.f - mv.w));
  orr.x = f2bf(cur.x * mr.x + prev.x * (1.f - mr.x));
  orr.y = f2bf(cur.y * mr.y + prev.y * (1.f - mr.y));
  orr.z = f2bf(cur.z * mr.z + prev.z * (1.f - mr.z));
  orr.w = f2bf(cur.w * mr.w + prev.w * (1.f - mr.w));
  xk[i] = ok; xv[i] = ov; xr[i] = orr;
}

// ---------------- bf16 NT GEMM: C[M,N] = A[M,K] * B[N,K]^T ----------------
// 128x128 tile, BK=32, DOUBLE-BUFFERED global_load_lds staging (prefetch tile
// k+1 while computing tile k -> hides staging latency exposed at ~2 blocks/CU),
// 32x32x16 bf16 MFMA, 4 waves x (2x2 of 32x32) sub-tiles.
// LDS XOR-swizzle carried over. EPI: 0 = fp32; 1 = sigmoid bf16; 2 = bf16.

#define TM 128
#define TN 128
#define TK 32

template <int EPI>
__global__ __launch_bounds__(256) void gemm_bt(
    const unsigned short* __restrict__ A, const unsigned short* __restrict__ B,
    float* __restrict__ Cf, unsigned short* __restrict__ Cb,
    int M, int N, int K) {
  __shared__ unsigned short lA[2][TM * TK];  // 2 x 8 KiB
  __shared__ unsigned short lB[2][TN * TK];  // 2 x 8 KiB

  const int tid = threadIdx.x;
  const int wave = tid >> 6;
  const int lane = tid & 63;
  const int bm = blockIdx.x * TM;
  const int bn = blockIdx.y * TN;
  const int wm = (wave >> 1) * 64;     // wave's 64x64 sub-tile
  const int wn = (wave & 1) * 64;
  const int lrow = lane & 31;          // m/n within a 32-tile
  const int lq = lane >> 5;            // k-chunk half selector (0/1)

  f32x16 acc[2][2] = {};

  // staging: seg in {wave, wave+4}; row = seg*16 + (lane>>2); slot = lane&3
  const int st_row0 = wave * 16 + (lane >> 2);
  const int st_row1 = (wave + 4) * 16 + (lane >> 2);
  const int st_c0 = (lane & 3) ^ ((st_row0 >> 1) & 3);
  const int st_c1 = (lane & 3) ^ ((st_row1 >> 1) & 3);
  const unsigned short* pA0 = A + (long long)(bm + st_row0) * K + st_c0 * 8;
  const unsigned short* pA1 = A + (long long)(bm + st_row1) * K + st_c1 * 8;
  const unsigned short* pB0 = B + (long long)(bn + st_row0) * K + st_c0 * 8;
  const unsigned short* pB1 = B + (long long)(bn + st_row1) * K + st_c1 * 8;

  // fragment LDS offsets (loop-invariant): row r, chunk c -> r*TK + (c^((r>>1)&3))*8
  int offA[2][2], offB[2][2];
#pragma unroll
  for (int t = 0; t < 2; ++t)
#pragma unroll
    for (int h = 0; h < 2; ++h) {
      int ar = wm + t * 32 + lrow;
      int br = wn + t * 32 + lrow;
      int c = h * 2 + lq;
      offA[t][h] = ar * TK + ((c ^ ((ar >> 1) & 3)) * 8);
      offB[t][h] = br * TK + ((c ^ ((br >> 1) & 3)) * 8);
    }

  // prologue: stage tile 0 into buffer 0
  gload_lds16(pA0, &lA[0][wave * 512]);
  gload_lds16(pA1, &lA[0][(wave + 4) * 512]);
  gload_lds16(pB0, &lB[0][wave * 512]);
  gload_lds16(pB1, &lB[0][(wave + 4) * 512]);
  pA0 += TK; pA1 += TK; pB0 += TK; pB1 += TK;

  int p = 0;
  for (int k0 = 0; k0 < K; k0 += TK) {
    __syncthreads();   // buf[p] staging complete (vmcnt drain), buf[p^1] free
    if (k0 + TK < K) { // prefetch next tile into buf[p^1] — overlaps compute
      gload_lds16(pA0, &lA[p ^ 1][wave * 512]);
      gload_lds16(pA1, &lA[p ^ 1][(wave + 4) * 512]);
      gload_lds16(pB0, &lB[p ^ 1][wave * 512]);
      gload_lds16(pB1, &lB[p ^ 1][(wave + 4) * 512]);
      pA0 += TK; pA1 += TK; pB0 += TK; pB1 += TK;
    }

    s16x8 af[2][2], bfr[2][2];
#pragma unroll
    for (int t = 0; t < 2; ++t)
#pragma unroll
      for (int h = 0; h < 2; ++h) {
        af[t][h]  = *(const s16x8*)&lA[p][offA[t][h]];
        bfr[t][h] = *(const s16x8*)&lB[p][offB[t][h]];
      }
#pragma unroll
    for (int h = 0; h < 2; ++h)
#pragma unroll
      for (int mt = 0; mt < 2; ++mt)
#pragma unroll
        for (int nt = 0; nt < 2; ++nt)
          acc[mt][nt] = __builtin_amdgcn_mfma_f32_32x32x16_bf16(
              af[mt][h], bfr[nt][h], acc[mt][nt], 0, 0, 0);
    p ^= 1;
  }

  // epilogue: 32x32 C/D layout col=lane&31, row=(reg&3)+8*(reg>>2)+4*(lane>>5)
#pragma unroll
  for (int mt = 0; mt < 2; ++mt)
#pragma unroll
    for (int nt = 0; nt < 2; ++nt)
#pragma unroll
      for (int r = 0; r < 16; ++r) {
        int row = bm + wm + mt * 32 + (r & 3) + 8 * (r >> 2) + 4 * lq;
        int col = bn + wn + nt * 32 + lrow;
        float v = acc[mt][nt][r];
        long long idx = (long long)row * N + col;
        if (EPI == 0) {
          Cf[idx] = v;
        } else if (EPI == 1) {
          float s = 1.f / (1.f + __expf(-v));
          Cb[idx] = f2bf(s);
        } else {
          Cb[idx] = f2bf(v);
        }
      }
}

// ---------------- chunked WKV scan (k now bf16) ----------------

#define NEG_INF_F (-1e38f)

__global__ void scan_phase1(const unsigned short* __restrict__ kb,
                            const unsigned short* __restrict__ vb,
                            const float* __restrict__ td,
                            float* __restrict__ locN, float* __restrict__ locD,
                            float* __restrict__ locM,
                            int S, int D, int C, int L) {
  int t = blockIdx.x * blockDim.x + threadIdx.x;  // over B*C*D
  int d = t % D;
  int c = (t / D) % C;
  int b = t / (D * C);
  float w = -__expf(td[d]);
  float num = 0.f, den = 0.f, m = NEG_INF_F;
  long long base = ((long long)(b * S + c * L)) * D + d;
  for (int i = 0; i < L; ++i) {
    float kk = bf2f(kb[base]);
    float vv = bf2f(vb[base]);
    base += D;
    float mn = fmaxf(m + w, kk);
    float e1 = __expf(m + w - mn);
    float e2 = __expf(kk - mn);
    num = e1 * num + e2 * vv;
    den = e1 * den + e2;
    m = mn;
  }
  int o = (b * C + c) * D + d;
  locN[o] = num; locD[o] = den; locM[o] = m;
}

__global__ void scan_phase2(const float* __restrict__ td,
                            const float* __restrict__ locN, const float* __restrict__ locD,
                            const float* __restrict__ locM,
                            float* __restrict__ inN, float* __restrict__ inD,
                            float* __restrict__ inM,
                            int Bc, int D, int C, int L) {
  int t = blockIdx.x * blockDim.x + threadIdx.x;  // over B*D
  if (t >= Bc * D) return;
  int d = t % D, b = t / D;
  float w = -__expf(td[d]);
  float Lw = (float)L * w;
  float num = 0.f, den = 0.f, m = NEG_INF_F;
  for (int c = 0; c < C; ++c) {
    int o = (b * C + c) * D + d;
    inN[o] = num; inD[o] = den; inM[o] = m;
    float sm = m + Lw;                 // decay incoming state over whole chunk
    float lm = locM[o];
    float m2 = fmaxf(sm, lm);
    float e1 = __expf(sm - m2);
    float e2 = __expf(lm - m2);
    num = e1 * num + e2 * locN[o];
    den = e1 * den + e2 * locD[o];
    m = m2;
  }
}

__global__ void scan_phase3(const unsigned short* __restrict__ kb,
                            const unsigned short* __restrict__ vb,
                            const unsigned short* __restrict__ rb,
                            const float* __restrict__ td, const float* __restrict__ tfirst,
                            const float* __restrict__ inN, const float* __restrict__ inD,
                            const float* __restrict__ inM,
                            unsigned short* __restrict__ rr,
                            int S, int D, int C, int L) {
  int t = blockIdx.x * blockDim.x + threadIdx.x;  // over B*C*D
  int d = t % D;
  int c = (t / D) % C;
  int b = t / (D * C);
  float w = -__expf(td[d]);
  float tfd = tfirst[d];
  int o = (b * C + c) * D + d;
  float num = inN[o], den = inD[o], m = inM[o];
  long long base = ((long long)(b * S + c * L)) * D + d;
  for (int i = 0; i < L; ++i) {
    float kk = bf2f(kb[base]);
    float vv = bf2f(vb[base]);
    float rv = bf2f(rb[base]);
    float ktf = kk + tfd;
    float mo = fmaxf(m, ktf);
    float e1 = __expf(m - mo);
    float e2 = __expf(ktf - mo);
    float out = (e1 * num + e2 * vv) / (e1 * den + e2);
    rr[base] = f2bf(out * rv);
    float mn = fmaxf(m + w, kk);
    e1 = __expf(m + w - mn);
    e2 = __expf(kk - mn);
    num = e1 * num + e2 * vv;
    den = e1 * den + e2;
    m = mn;
    base += D;
  }
}

// ---------------- launch ----------------

extern "C" void kernel_launch(void* const* d_in, const int* in_sizes, int n_in,
                              void* d_out, int out_size, void* d_ws, size_t ws_size,
                              hipStream_t stream) {
  const float* hidden = (const float*)d_in[0];
  const float* td  = (const float*)d_in[1];
  const float* tfi = (const float*)d_in[2];
  const float* tmk = (const float*)d_in[3];
  const float* tmv = (const float*)d_in[4];
  const float* tmr = (const float*)d_in[5];
  const float* Wk  = (const float*)d_in[6];
  const float* Wv  = (const float*)d_in[7];
  const float* Wr  = (const float*)d_in[8];
  const float* Wo  = (const float*)d_in[9];
  float* out = (float*)d_out;

  const int H = in_sizes[1];                 // 2048
  const int D = H;
  const long long BS = (long long)in_sizes[0] / H;  // 8192 = B*S
  const int S = 2048;
  const int B = (int)(BS / S);               // 4
  const int C = 32, L = S / C;               // 32 chunks of 64

  // workspace layout (110 MiB, proven safe):
  //   W_b [0,8) | X [8,40) | Y [40,72) | Z [72,104) | states [104,110)
  // rotation: prep3 -> X=xk, Y=xv, Z=xr
  //   gemm k: X -> kb (d_out, bf16, first 32 MiB); gemm v: Y -> X; gemm r: Z -> Y
  //   scan: kb, X(v), Y(r) -> Z (rr);  gemm o: Z -> d_out fp32 (kb dead)
  char* ws = (char*)d_ws;
  const size_t MB = 1u << 20;
  unsigned short* W_b = (unsigned short*)(ws + 0 * MB);
  unsigned short* X   = (unsigned short*)(ws + 8 * MB);
  unsigned short* Y   = (unsigned short*)(ws + 40 * MB);
  unsigned short* Z   = (unsigned short*)(ws + 72 * MB);
  float* locN         = (float*)(ws + 104 * MB);
  float* locD         = (float*)(ws + 105 * MB);
  float* locM         = (float*)(ws + 106 * MB);
  float* inN          = (float*)(ws + 107 * MB);
  float* inD          = (float*)(ws + 108 * MB);
  float* inM          = (float*)(ws + 109 * MB);
  unsigned short* kb  = (unsigned short*)out;   // bf16 k scratch in d_out

  int n4w = H * H / 4;
  int cbk = (n4w + 255) / 256;
  long long total4 = BS * H / 4;
  int pbk = (int)((total4 + 255) / 256);
  dim3 g((unsigned)(BS / TM), (unsigned)(D / TN));

  // fused time-shift mix (one pass over hidden)
  prep_mix3<<<pbk, 256, 0, stream>>>((const float4*)hidden,
                                     (const float4*)tmk, (const float4*)tmv, (const float4*)tmr,
                                     (ushort4*)X, (ushort4*)Y, (ushort4*)Z, S, H / 4, total4);

  // k = xk @ Wk^T  (bf16 -> d_out scratch)
  conv_bf16<<<cbk, 256, 0, stream>>>((const float4*)Wk, (ushort4*)W_b, n4w);
  gemm_bt<2><<<g, 256, 0, stream>>>(X, W_b, nullptr, kb, (int)BS, D, H);

  // v = xv @ Wv^T  (bf16 -> X)
  conv_bf16<<<cbk, 256, 0, stream>>>((const float4*)Wv, (ushort4*)W_b, n4w);
  gemm_bt<2><<<g, 256, 0, stream>>>(Y, W_b, nullptr, X, (int)BS, D, H);

  // r = sigmoid(xr @ Wr^T)  (bf16 -> Y)
  conv_bf16<<<cbk, 256, 0, stream>>>((const float4*)Wr, (ushort4*)W_b, n4w);
  gemm_bt<1><<<g, 256, 0, stream>>>(Z, W_b, nullptr, Y, (int)BS, D, H);

  // chunked WKV scan, fused r * rwkv -> Z (bf16)
  int nscan = B * C * D;
  scan_phase1<<<nscan / 256, 256, 0, stream>>>(kb, X, td, locN, locD, locM, S, D, C, L);
  scan_phase2<<<(B * D + 255) / 256, 256, 0, stream>>>(td, locN, locD, locM, inN, inD, inM, B, D, C, L);
  scan_phase3<<<nscan / 256, 256, 0, stream>>>(kb, X, Y, td, tfi, inN, inD, inM, Z, S, D, C, L);

  // out = (r * rwkv) @ Wo^T  (fp32 -> d_out; kb dead now)
  conv_bf16<<<cbk, 256, 0, stream>>>((const float4*)Wo, (ushort4*)W_b, n4w);
  gemm_bt<0><<<g, 256, 0, stream>>>(Z, W_b, out, nullptr, (int)BS, H, D);
}